// Round 4
// baseline (3382.287 us; speedup 1.0000x reference)
//
#include <hip/hip_runtime.h>
#include <math.h>

namespace {
constexpr int NIMG = 16;
constexpr int ICH  = 3;
constexpr int OCH  = 64;
constexpr int KS   = 7;
constexpr int H    = 512;
constexpr int W    = 512;
constexpr int TH   = 32;   // output tile height per block
constexpr int TW   = 64;   // output tile width per block
constexpr int XH   = TH + 6;
constexpr int XW   = TW + 6;
constexpr int XP   = 76;   // LDS pitch (floats), 16B-aligned rows, banks spread
constexpr int NW   = KS * KS * OCH;   // 3136 weights
}

typedef float f32x4 __attribute__((ext_vector_type(4)));

// ---- pass 1: ridgelet filter bank -> d_ws, layout [g][kh][kw][c], oc=g*4+c ----
__global__ void make_weights(const float* __restrict__ scales,
                             const float* __restrict__ dirs,
                             const float* __restrict__ poss,
                             float* __restrict__ w)
{
    for (int i = threadIdx.x; i < NW; i += 256) {
        const int g  = i / 196;           // oc group (4 ch)
        const int r  = i - g * 196;
        const int kh = r / 28;
        const int r2 = r - kh * 28;
        const int kw = r2 >> 2;
        const int c  = r2 & 3;
        const int oc = g * 4 + c;
        const float d  = dirs[oc];
        const float tc = ((float)(kh - 3) * cosf(d) + (float)(kw - 3) * sinf(d)
                          - poss[oc]) / scales[oc];
        const float t2 = tc * tc;
        w[i] = expf(-0.5f * t2) - 0.5f * expf(-0.125f * t2);
    }
}

// ---- pass 2: conv. weights come in via wave-uniform reads -> s_load ----
__global__ __launch_bounds__(256)
void ridgelet_conv(const float* __restrict__ x,
                   const float* __restrict__ w,
                   float* __restrict__ out)
{
    __shared__ float xs[XH][XP];          // channel-summed input tile (padded)

    const int tid = threadIdx.x;
    const int tw0 = blockIdx.x * TW;
    const int th0 = blockIdx.y * TH;
    const int n   = blockIdx.z;

    // stage channel-summed, zero-padded input tile
    const float* xb = x + (size_t)n * ICH * H * W;
    for (int idx = tid; idx < XH * XW; idx += 256) {
        const int r  = idx / XW;
        const int c  = idx - r * XW;
        const int gh = th0 + r - 3;
        const int gw = tw0 + c - 3;
        float s = 0.0f;
        if ((unsigned)gh < (unsigned)H && (unsigned)gw < (unsigned)W) {
            const size_t o = (size_t)gh * W + gw;
            s = xb[o] + xb[o + (size_t)H * W] + xb[o + 2 * (size_t)H * W];
        }
        xs[r][c] = s;
    }
    __syncthreads();

    // thread = 1 output row x 8 output cols; 16 iterations x 4 oc
    const int tx = tid & 7;
    const int ty = tid >> 3;
    const int cb = tx * 8;

    float* ob = out + (size_t)n * OCH * H * W
                    + (size_t)(th0 + ty) * W + (tw0 + cb);

    #pragma unroll 1
    for (int g = 0; g < 16; ++g) {
        const float* __restrict__ wg = w + g * 196;   // uniform -> scalar loads

        float acc[4][8];
        #pragma unroll
        for (int c = 0; c < 4; ++c)
            #pragma unroll
            for (int j = 0; j < 8; ++j)
                acc[c][j] = 0.0f;

        #pragma unroll
        for (int kh = 0; kh < KS; ++kh) {
            float win[16];
            const float* rp = &xs[ty + kh][cb];
            *(float4*)&win[0]  = *(const float4*)(rp);
            *(float4*)&win[4]  = *(const float4*)(rp + 4);
            *(float4*)&win[8]  = *(const float4*)(rp + 8);
            *(float4*)&win[12] = *(const float4*)(rp + 12);

            #pragma unroll
            for (int kw = 0; kw < KS; ++kw) {
                const float w0 = wg[kh * 28 + kw * 4 + 0];
                const float w1 = wg[kh * 28 + kw * 4 + 1];
                const float w2 = wg[kh * 28 + kw * 4 + 2];
                const float w3 = wg[kh * 28 + kw * 4 + 3];
                #pragma unroll
                for (int j = 0; j < 8; ++j) {
                    const float v = win[j + kw];
                    acc[0][j] = fmaf(v, w0, acc[0][j]);
                    acc[1][j] = fmaf(v, w1, acc[1][j]);
                    acc[2][j] = fmaf(v, w2, acc[2][j]);
                    acc[3][j] = fmaf(v, w3, acc[3][j]);
                }
            }
        }

        // store: 2 nontemporal 16B stores per oc (output never re-read)
        #pragma unroll
        for (int c = 0; c < 4; ++c) {
            float* p = ob + (size_t)(g * 4 + c) * (H * W);
            f32x4 s0 = { acc[c][0], acc[c][1], acc[c][2], acc[c][3] };
            f32x4 s1 = { acc[c][4], acc[c][5], acc[c][6], acc[c][7] };
            __builtin_nontemporal_store(s0, (f32x4*)(p));
            __builtin_nontemporal_store(s1, (f32x4*)(p + 4));
        }
    }
}

extern "C" void kernel_launch(void* const* d_in, const int* in_sizes, int n_in,
                              void* d_out, int out_size, void* d_ws, size_t ws_size,
                              hipStream_t stream)
{
    const float* x  = (const float*)d_in[0];
    const float* sc = (const float*)d_in[1];
    const float* di = (const float*)d_in[2];
    const float* po = (const float*)d_in[3];
    float* outp     = (float*)d_out;
    float* wbuf     = (float*)d_ws;       // 3136 floats = 12.5 KB

    make_weights<<<dim3(1), dim3(256), 0, stream>>>(sc, di, po, wbuf);

    dim3 grid(W / TW, H / TH, NIMG);      // 8 x 16 x 16 = 2048 blocks
    ridgelet_conv<<<grid, dim3(256), 0, stream>>>(x, wbuf, outp);
}

// Round 5
// 360.713 us; speedup vs baseline: 9.3767x; 9.3767x over previous
//
#include <hip/hip_runtime.h>
#include <math.h>

namespace {
constexpr int NIMG = 16;
constexpr int ICH  = 3;
constexpr int OCH  = 64;
constexpr int KS   = 7;
constexpr int H    = 512;
constexpr int W    = 512;
constexpr int TH   = 32;   // output tile height per block
constexpr int TW   = 64;   // output tile width per block
constexpr int XH   = TH + 6;
constexpr int XW   = TW + 6;
constexpr int XP   = 76;   // LDS pitch (floats): bank quads (3*ty+2*tx)%8 balanced
}

typedef float f32x4 __attribute__((ext_vector_type(4)));

__global__ __launch_bounds__(256)     // NO min-wave hint: let allocator breathe
void ridgelet_conv(const float* __restrict__ x,
                   const float* __restrict__ scales,
                   const float* __restrict__ dirs,
                   const float* __restrict__ poss,
                   float* __restrict__ out)
{
    __shared__ float xs[XH][XP];          // channel-summed input tile (padded)
    __shared__ float wl[KS * KS][OCH];    // filter bank [tap][oc]

    const int tid = threadIdx.x;
    const int tw0 = blockIdx.x * TW;
    const int th0 = blockIdx.y * TH;
    const int n   = blockIdx.z;

    // ---- generate filter bank into LDS (~12 exp-pairs/thread, 1-2% of work) ----
    for (int idx = tid; idx < KS * KS * OCH; idx += 256) {
        const int k  = idx >> 6;          // tap 0..48
        const int oc = idx & 63;
        const int kh = k / 7;
        const int kw = k - kh * 7;
        const float d  = dirs[oc];
        const float tc = ((float)(kh - 3) * cosf(d) + (float)(kw - 3) * sinf(d)
                          - poss[oc]) / scales[oc];
        const float t2 = tc * tc;
        wl[k][oc] = expf(-0.5f * t2) - 0.5f * expf(-0.125f * t2);
    }

    // ---- stage channel-summed, zero-padded input tile ----
    const float* xb = x + (size_t)n * ICH * H * W;
    for (int idx = tid; idx < XH * XW; idx += 256) {
        const int r  = idx / XW;
        const int c  = idx - r * XW;
        const int gh = th0 + r - 3;
        const int gw = tw0 + c - 3;
        float s = 0.0f;
        if ((unsigned)gh < (unsigned)H && (unsigned)gw < (unsigned)W) {
            const size_t o = (size_t)gh * W + gw;
            s = xb[o] + xb[o + (size_t)H * W] + xb[o + 2 * (size_t)H * W];
        }
        xs[r][c] = s;
    }
    __syncthreads();

    // ---- compute: thread = 1 output row x 8 cols; 8 iterations x 8 oc ----
    const int tx = tid & 7;
    const int ty = tid >> 3;
    const int cb = tx * 8;

    float* ob = out + (size_t)n * OCH * H * W
                    + (size_t)(th0 + ty) * W + (tw0 + cb);

    #pragma unroll 1
    for (int g = 0; g < 8; ++g) {
        const int ocb = g * 8;            // this iteration's 8 output channels

        float acc[8][8];                  // [oc][px]  = 64 VGPR
        #pragma unroll
        for (int c = 0; c < 8; ++c)
            #pragma unroll
            for (int j = 0; j < 8; ++j)
                acc[c][j] = 0.0f;

        #pragma unroll 1
        for (int kh = 0; kh < KS; ++kh) {
            float win[16];
            const float* rp = &xs[ty + kh][cb];
            *(f32x4*)&win[0]  = *(const f32x4*)(rp);
            *(f32x4*)&win[4]  = *(const f32x4*)(rp + 4);
            *(f32x4*)&win[8]  = *(const f32x4*)(rp + 8);
            *(f32x4*)&win[12] = *(const f32x4*)(rp + 12);

            #pragma unroll
            for (int kw = 0; kw < KS; ++kw) {
                // 8 channels' weights: wave-uniform LDS address -> broadcast
                const f32x4 wa = *(const f32x4*)&wl[kh * 7 + kw][ocb];
                const f32x4 wb = *(const f32x4*)&wl[kh * 7 + kw][ocb + 4];
                #pragma unroll
                for (int j = 0; j < 8; ++j) {
                    const float v = win[j + kw];
                    acc[0][j] = fmaf(v, wa.x, acc[0][j]);
                    acc[1][j] = fmaf(v, wa.y, acc[1][j]);
                    acc[2][j] = fmaf(v, wa.z, acc[2][j]);
                    acc[3][j] = fmaf(v, wa.w, acc[3][j]);
                    acc[4][j] = fmaf(v, wb.x, acc[4][j]);
                    acc[5][j] = fmaf(v, wb.y, acc[5][j]);
                    acc[6][j] = fmaf(v, wb.z, acc[6][j]);
                    acc[7][j] = fmaf(v, wb.w, acc[7][j]);
                }
            }
        }

        // ---- store: 2 nontemporal 16B stores per oc (never re-read) ----
        #pragma unroll
        for (int c = 0; c < 8; ++c) {
            float* p = ob + (size_t)(ocb + c) * (H * W);
            f32x4 s0 = { acc[c][0], acc[c][1], acc[c][2], acc[c][3] };
            f32x4 s1 = { acc[c][4], acc[c][5], acc[c][6], acc[c][7] };
            __builtin_nontemporal_store(s0, (f32x4*)(p));
            __builtin_nontemporal_store(s1, (f32x4*)(p + 4));
        }
    }
}

extern "C" void kernel_launch(void* const* d_in, const int* in_sizes, int n_in,
                              void* d_out, int out_size, void* d_ws, size_t ws_size,
                              hipStream_t stream)
{
    const float* x  = (const float*)d_in[0];
    const float* sc = (const float*)d_in[1];
    const float* di = (const float*)d_in[2];
    const float* po = (const float*)d_in[3];
    float* outp     = (float*)d_out;

    dim3 grid(W / TW, H / TH, NIMG);      // 8 x 16 x 16 = 2048 blocks
    ridgelet_conv<<<grid, dim3(256), 0, stream>>>(x, sc, di, po, outp);
}

// Round 6
// 354.424 us; speedup vs baseline: 9.5431x; 1.0177x over previous
//
#include <hip/hip_runtime.h>
#include <math.h>

namespace {
constexpr int NIMG = 16;
constexpr int ICH  = 3;
constexpr int OCH  = 64;
constexpr int KS   = 7;
constexpr int H    = 512;
constexpr int W    = 512;
constexpr int TH   = 32;   // output tile height per block
constexpr int TW   = 64;   // output tile width per block
constexpr int XH   = TH + 6;   // 38
constexpr int XW   = TW + 6;   // 70
constexpr int XPH  = 72;       // f16 pitch: 144B rows (16B aligned); all cols staged (no NaN pads)
}

typedef float    f32x4 __attribute__((ext_vector_type(4)));
typedef _Float16 h2    __attribute__((ext_vector_type(2)));
typedef _Float16 h8    __attribute__((ext_vector_type(8)));

__global__ __launch_bounds__(256)
void ridgelet_conv(const float* __restrict__ x,
                   const float* __restrict__ scales,
                   const float* __restrict__ dirs,
                   const float* __restrict__ poss,
                   float* __restrict__ out)
{
    __shared__ _Float16 xs[XH][XPH];     // channel-summed tile, f16
    __shared__ h2 wp[KS][4][OCH];        // [kh][kw-pair][oc]; pair=(w(2p),w(2p+1)), w(7)=0

    const int tid = threadIdx.x;
    const int tw0 = blockIdx.x * TW;
    const int th0 = blockIdx.y * TH;
    const int n   = blockIdx.z;

    // ---- filter bank, pair-packed f16 (28 exp/thread, negligible) ----
    for (int idx = tid; idx < KS * 4 * OCH; idx += 256) {
        const int kh = idx >> 8;          // /(4*64)
        const int r  = idx & 255;
        const int p  = r >> 6;
        const int oc = r & 63;
        const float d   = dirs[oc];
        const float cd  = cosf(d), sd = sinf(d);
        const float inv = 1.0f / scales[oc];
        const float po  = poss[oc];
        float wv[2];
        #pragma unroll
        for (int t = 0; t < 2; ++t) {
            const int kw = 2 * p + t;
            if (kw < KS) {
                const float tc = ((float)(kh - 3) * cd + (float)(kw - 3) * sd - po) * inv;
                const float t2 = tc * tc;
                wv[t] = expf(-0.5f * t2) - 0.5f * expf(-0.125f * t2);
            } else {
                wv[t] = 0.0f;
            }
        }
        wp[kh][p][oc] = h2{(_Float16)wv[0], (_Float16)wv[1]};
    }

    // ---- stage channel-summed tile as f16 (ALL XPH cols -> no garbage reads) ----
    const float* xb = x + (size_t)n * ICH * H * W;
    for (int idx = tid; idx < XH * XPH; idx += 256) {
        const int r  = idx / XPH;
        const int c  = idx - r * XPH;
        const int gh = th0 + r - 3;
        const int gw = tw0 + c - 3;
        float s = 0.0f;
        if ((unsigned)gh < (unsigned)H && (unsigned)gw < (unsigned)W) {
            const size_t o = (size_t)gh * W + gw;
            s = xb[o] + xb[o + (size_t)H * W] + xb[o + 2 * (size_t)H * W];
        }
        xs[r][c] = (_Float16)s;
    }
    __syncthreads();

    // ---- compute: thread = 1 row x 8 cols; 8 iterations x 8 oc; dot2 taps ----
    const int tx = tid & 7;
    const int ty = tid >> 3;
    const int cb = tx * 8;

    float* ob = out + (size_t)n * OCH * H * W
                    + (size_t)(th0 + ty) * W + (tw0 + cb);

    #pragma unroll 1
    for (int g = 0; g < 8; ++g) {
        const int ocb = g * 8;

        float acc[8][8];                  // [oc][px]
        #pragma unroll
        for (int c = 0; c < 8; ++c)
            #pragma unroll
            for (int j = 0; j < 8; ++j)
                acc[c][j] = 0.0f;

        #pragma unroll 1
        for (int kh = 0; kh < KS; ++kh) {
            const _Float16* rp = &xs[ty + kh][cb];
            const h8 w0 = *(const h8*)(rp);        // halfs 0..7
            const h8 w1 = *(const h8*)(rp + 8);    // halfs 8..15

            h2 pe[8];   // (x[2i],   x[2i+1])
            h2 po_[7];  // (x[2i+1], x[2i+2])
            #pragma unroll
            for (int i = 0; i < 4; ++i) pe[i]     = h2{w0[2*i], w0[2*i+1]};
            #pragma unroll
            for (int i = 0; i < 4; ++i) pe[4 + i] = h2{w1[2*i], w1[2*i+1]};
            #pragma unroll
            for (int i = 0; i < 7; ++i) {
                const _Float16 lo = (2*i + 1 < 8) ? w0[2*i + 1] : w1[2*i - 7];
                const _Float16 hi = (2*i + 2 < 8) ? w0[2*i + 2] : w1[2*i - 6];
                po_[i] = h2{lo, hi};
            }

            #pragma unroll
            for (int p = 0; p < 4; ++p) {
                const h8 wa = *(const h8*)&wp[kh][p][ocb];       // oc 0..3 pairs
                const h8 wb = *(const h8*)&wp[kh][p][ocb + 4];   // oc 4..7 pairs
                #pragma unroll
                for (int c = 0; c < 8; ++c) {
                    const h2 wc = (c < 4) ? h2{wa[2*c], wa[2*c + 1]}
                                          : h2{wb[2*(c-4)], wb[2*(c-4) + 1]};
                    #pragma unroll
                    for (int j = 0; j < 8; ++j) {
                        const int k0 = j + 2 * p;
                        const h2 xv = (k0 & 1) ? po_[k0 >> 1] : pe[k0 >> 1];
                        acc[c][j] = __builtin_amdgcn_fdot2(xv, wc, acc[c][j], false);
                    }
                }
            }
        }

        // ---- store: 2 nontemporal 16B stores per oc (never re-read) ----
        #pragma unroll
        for (int c = 0; c < 8; ++c) {
            float* pp = ob + (size_t)(ocb + c) * (H * W);
            f32x4 s0 = { acc[c][0], acc[c][1], acc[c][2], acc[c][3] };
            f32x4 s1 = { acc[c][4], acc[c][5], acc[c][6], acc[c][7] };
            __builtin_nontemporal_store(s0, (f32x4*)(pp));
            __builtin_nontemporal_store(s1, (f32x4*)(pp + 4));
        }
    }
}

extern "C" void kernel_launch(void* const* d_in, const int* in_sizes, int n_in,
                              void* d_out, int out_size, void* d_ws, size_t ws_size,
                              hipStream_t stream)
{
    const float* x  = (const float*)d_in[0];
    const float* sc = (const float*)d_in[1];
    const float* di = (const float*)d_in[2];
    const float* po = (const float*)d_in[3];
    float* outp     = (float*)d_out;

    dim3 grid(W / TW, H / TH, NIMG);      // 8 x 16 x 16 = 2048 blocks
    ridgelet_conv<<<grid, dim3(256), 0, stream>>>(x, sc, di, po, outp);
}

// Round 7
// 348.474 us; speedup vs baseline: 9.7060x; 1.0171x over previous
//
#include <hip/hip_runtime.h>
#include <math.h>

namespace {
constexpr int NIMG = 16;
constexpr int ICH  = 3;
constexpr int OCH  = 64;
constexpr int KS   = 7;
constexpr int H    = 512;
constexpr int W    = 512;
constexpr int TH   = 32;   // output tile height per block
constexpr int TW   = 64;   // output tile width per block
constexpr int XH   = TH + 6;   // 38
constexpr int XW   = TW + 6;   // 70 valid halo cols
constexpr int XP   = 76;   // LDS pitch (floats); cols >= XW zero-staged
}

typedef float f32x4 __attribute__((ext_vector_type(4)));

__global__ __launch_bounds__(256)
void ridgelet_conv(const float* __restrict__ x,
                   const float* __restrict__ scales,
                   const float* __restrict__ dirs,
                   const float* __restrict__ poss,
                   float* __restrict__ out)
{
    __shared__ float xs[XH][XP];          // channel-summed input tile (padded)
    __shared__ float wl[KS * KS][OCH];    // filter bank [tap][oc]

    const int tid = threadIdx.x;
    const int tw0 = blockIdx.x * TW;
    const int th0 = blockIdx.y * TH;
    const int n   = blockIdx.z;

    // ---- generate filter bank into LDS (~12 exp-pairs/thread) ----
    for (int idx = tid; idx < KS * KS * OCH; idx += 256) {
        const int k  = idx >> 6;          // tap 0..48
        const int oc = idx & 63;
        const int kh = k / 7;
        const int kw = k - kh * 7;
        const float d  = dirs[oc];
        const float tc = ((float)(kh - 3) * cosf(d) + (float)(kw - 3) * sinf(d)
                          - poss[oc]) / scales[oc];
        const float t2 = tc * tc;
        wl[k][oc] = expf(-0.5f * t2) - 0.5f * expf(-0.125f * t2);
    }

    // ---- stage channel-summed tile, FULL pitch (pad cols zeroed) ----
    const float* xb = x + (size_t)n * ICH * H * W;
    for (int idx = tid; idx < XH * XP; idx += 256) {
        const int r  = idx / XP;
        const int c  = idx - r * XP;
        const int gh = th0 + r - 3;
        const int gw = tw0 + c - 3;
        float s = 0.0f;
        if (c < XW && (unsigned)gh < (unsigned)H && (unsigned)gw < (unsigned)W) {
            const size_t o = (size_t)gh * W + gw;
            s = xb[o] + xb[o + (size_t)H * W] + xb[o + 2 * (size_t)H * W];
        }
        xs[r][c] = s;
    }
    __syncthreads();

    // ---- compute: thread = 2 rows x 4 cols (lane-contiguous stores) ----
    const int tx = tid & 15;              // 16 col groups x 4 floats = 64 cols
    const int ty = tid >> 4;              // 16 row groups x 2 rows  = 32 rows
    const int cb = tx * 4;                // local col base
    const int r0 = ty * 2;                // local row base

    float* ob = out + (size_t)n * OCH * H * W
                    + (size_t)(th0 + r0) * W + (tw0 + cb);

    #pragma unroll 1
    for (int g = 0; g < 8; ++g) {
        const int ocb = g * 8;            // this iteration's 8 output channels

        float acc[8][2][4];               // [oc][row][col] = 64 VGPR
        #pragma unroll
        for (int c = 0; c < 8; ++c)
            #pragma unroll
            for (int i = 0; i < 2; ++i)
                #pragma unroll
                for (int j = 0; j < 4; ++j)
                    acc[c][i][j] = 0.0f;

        #pragma unroll 1
        for (int kh = 0; kh < KS; ++kh) {
            float win[2][12];             // 2 rows x 12-col window (need 10)
            #pragma unroll
            for (int i = 0; i < 2; ++i) {
                const float* rp = &xs[r0 + i + kh][cb];
                *(f32x4*)&win[i][0] = *(const f32x4*)(rp);
                *(f32x4*)&win[i][4] = *(const f32x4*)(rp + 4);
                *(f32x4*)&win[i][8] = *(const f32x4*)(rp + 8);
            }

            #pragma unroll
            for (int kw = 0; kw < KS; ++kw) {
                // 8 channels' weights: wave-uniform LDS address -> broadcast
                const f32x4 wa = *(const f32x4*)&wl[kh * 7 + kw][ocb];
                const f32x4 wb = *(const f32x4*)&wl[kh * 7 + kw][ocb + 4];
                #pragma unroll
                for (int i = 0; i < 2; ++i) {
                    #pragma unroll
                    for (int j = 0; j < 4; ++j) {
                        const float v = win[i][j + kw];
                        acc[0][i][j] = fmaf(v, wa.x, acc[0][i][j]);
                        acc[1][i][j] = fmaf(v, wa.y, acc[1][i][j]);
                        acc[2][i][j] = fmaf(v, wa.z, acc[2][i][j]);
                        acc[3][i][j] = fmaf(v, wa.w, acc[3][i][j]);
                        acc[4][i][j] = fmaf(v, wb.x, acc[4][i][j]);
                        acc[5][i][j] = fmaf(v, wb.y, acc[5][i][j]);
                        acc[6][i][j] = fmaf(v, wb.z, acc[6][i][j]);
                        acc[7][i][j] = fmaf(v, wb.w, acc[7][i][j]);
                    }
                }
            }
        }

        // ---- store: every wave-inst is lane-contiguous (full 128B lines) ----
        #pragma unroll
        for (int c = 0; c < 8; ++c) {
            float* p = ob + (size_t)(ocb + c) * (H * W);
            #pragma unroll
            for (int i = 0; i < 2; ++i) {
                f32x4 s = { acc[c][i][0], acc[c][i][1], acc[c][i][2], acc[c][i][3] };
                __builtin_nontemporal_store(s, (f32x4*)(p + (size_t)i * W));
            }
        }
    }
}

extern "C" void kernel_launch(void* const* d_in, const int* in_sizes, int n_in,
                              void* d_out, int out_size, void* d_ws, size_t ws_size,
                              hipStream_t stream)
{
    const float* x  = (const float*)d_in[0];
    const float* sc = (const float*)d_in[1];
    const float* di = (const float*)d_in[2];
    const float* po = (const float*)d_in[3];
    float* outp     = (float*)d_out;

    dim3 grid(W / TW, H / TH, NIMG);      // 8 x 16 x 16 = 2048 blocks
    ridgelet_conv<<<grid, dim3(256), 0, stream>>>(x, sc, di, po, outp);
}

// Round 8
// 314.420 us; speedup vs baseline: 10.7572x; 1.1083x over previous
//
#include <hip/hip_runtime.h>
#include <math.h>

namespace {
constexpr int NIMG = 16;
constexpr int ICH  = 3;
constexpr int OCH  = 64;
constexpr int KS   = 7;
constexpr int H    = 512;
constexpr int W    = 512;
constexpr int TH   = 32;   // output tile height per block
constexpr int TW   = 64;   // output tile width per block
constexpr int XH   = TH + 6;   // 38
constexpr int XW   = TW + 6;   // 70 valid halo cols
constexpr int XP   = 76;       // LDS pitch (floats); cols >= XW zero-staged
constexpr int WSTR = 64;       // floats per (g,kh) weight group -> 256B aligned
constexpr int NWS  = 8 * KS * WSTR;   // 3584 slots
}

typedef float f32x4 __attribute__((ext_vector_type(4)));
typedef float f32x8 __attribute__((ext_vector_type(8)));

// ---- pass 1: filter bank -> d_ws. layout [(g*7+kh)*64 + kw*8 + c], oc=g*8+c ----
__global__ void make_weights(const float* __restrict__ scales,
                             const float* __restrict__ dirs,
                             const float* __restrict__ poss,
                             float* __restrict__ w)
{
    for (int i = threadIdx.x; i < NWS; i += 256) {
        const int g  = i / 448;           // 448 = 7*64 slots per g
        const int r  = i - g * 448;
        const int kh = r >> 6;
        const int r2 = r & 63;
        const int kw = r2 >> 3;
        const int c  = r2 & 7;
        float v = 0.0f;
        if (kw < KS) {
            const int oc = g * 8 + c;
            const float d  = dirs[oc];
            const float tc = ((float)(kh - 3) * cosf(d) + (float)(kw - 3) * sinf(d)
                              - poss[oc]) / scales[oc];
            const float t2 = tc * tc;
            v = expf(-0.5f * t2) - 0.5f * expf(-0.125f * t2);
        }
        w[i] = v;
    }
}

// ---- pass 2: conv with SGPR-resident weights (s_load_dwordx8) ----
__global__ __launch_bounds__(256)
void ridgelet_conv(const float* __restrict__ x,
                   const float* __restrict__ w,
                   float* __restrict__ out)
{
    __shared__ float xs[XH][XP];          // channel-summed input tile (padded)

    const int tid = threadIdx.x;
    const int tw0 = blockIdx.x * TW;
    const int th0 = blockIdx.y * TH;
    const int n   = blockIdx.z;

    // stage channel-summed tile, FULL pitch (pad cols zeroed)
    const float* xb = x + (size_t)n * ICH * H * W;
    for (int idx = tid; idx < XH * XP; idx += 256) {
        const int r  = idx / XP;
        const int c  = idx - r * XP;
        const int gh = th0 + r - 3;
        const int gw = tw0 + c - 3;
        float s = 0.0f;
        if (c < XW && (unsigned)gh < (unsigned)H && (unsigned)gw < (unsigned)W) {
            const size_t o = (size_t)gh * W + gw;
            s = xb[o] + xb[o + (size_t)H * W] + xb[o + 2 * (size_t)H * W];
        }
        xs[r][c] = s;
    }
    __syncthreads();

    // compute: thread = 2 rows x 4 cols (lane-contiguous stores)
    const int tx = tid & 15;
    const int ty = tid >> 4;
    const int cb = tx * 4;
    const int r0 = ty * 2;

    float* ob = out + (size_t)n * OCH * H * W
                    + (size_t)(th0 + r0) * W + (tw0 + cb);

    #pragma unroll 1
    for (int g = 0; g < 8; ++g) {
        const int ocb = g * 8;

        float acc[8][2][4];               // [oc][row][col] = 64 VGPR
        #pragma unroll
        for (int c = 0; c < 8; ++c)
            #pragma unroll
            for (int i = 0; i < 2; ++i)
                #pragma unroll
                for (int j = 0; j < 4; ++j)
                    acc[c][i][j] = 0.0f;

        #pragma unroll 1
        for (int kh = 0; kh < KS; ++kh) {
            // ---- 56 weights -> SGPRs. Loads + wait in ONE asm block so the
            // compiler cannot hoist consumers past the wait (rule #18). ----
            const float* wp = w + (size_t)(g * KS + kh) * WSTR;
            f32x8 wv0, wv1, wv2, wv3, wv4, wv5, wv6;
            asm volatile(
                "s_load_dwordx8 %0, %7, 0x00\n\t"
                "s_load_dwordx8 %1, %7, 0x20\n\t"
                "s_load_dwordx8 %2, %7, 0x40\n\t"
                "s_load_dwordx8 %3, %7, 0x60\n\t"
                "s_load_dwordx8 %4, %7, 0x80\n\t"
                "s_load_dwordx8 %5, %7, 0xa0\n\t"
                "s_load_dwordx8 %6, %7, 0xc0\n\t"
                "s_waitcnt lgkmcnt(0)"
                : "=&s"(wv0), "=&s"(wv1), "=&s"(wv2), "=&s"(wv3),
                  "=&s"(wv4), "=&s"(wv5), "=&s"(wv6)
                : "s"(wp));
            const f32x8 wk[7] = { wv0, wv1, wv2, wv3, wv4, wv5, wv6 };

            // ---- window: 2 rows x 12 floats from LDS ----
            float win[2][12];
            #pragma unroll
            for (int i = 0; i < 2; ++i) {
                const float* rp = &xs[r0 + i + kh][cb];
                *(f32x4*)&win[i][0] = *(const f32x4*)(rp);
                *(f32x4*)&win[i][4] = *(const f32x4*)(rp + 4);
                *(f32x4*)&win[i][8] = *(const f32x4*)(rp + 8);
            }

            #pragma unroll
            for (int kw = 0; kw < KS; ++kw) {       // full unroll -> wk[kw] static
                const f32x8 wv = wk[kw];
                #pragma unroll
                for (int i = 0; i < 2; ++i) {
                    #pragma unroll
                    for (int j = 0; j < 4; ++j) {
                        const float v = win[i][j + kw];
                        #pragma unroll
                        for (int c = 0; c < 8; ++c)
                            acc[c][i][j] = fmaf(v, wv[c], acc[c][i][j]);
                    }
                }
            }
        }

        // ---- store: lane-contiguous nontemporal 16B stores ----
        #pragma unroll
        for (int c = 0; c < 8; ++c) {
            float* p = ob + (size_t)(ocb + c) * (H * W);
            #pragma unroll
            for (int i = 0; i < 2; ++i) {
                f32x4 s = { acc[c][i][0], acc[c][i][1], acc[c][i][2], acc[c][i][3] };
                __builtin_nontemporal_store(s, (f32x4*)(p + (size_t)i * W));
            }
        }
    }
}

extern "C" void kernel_launch(void* const* d_in, const int* in_sizes, int n_in,
                              void* d_out, int out_size, void* d_ws, size_t ws_size,
                              hipStream_t stream)
{
    const float* x  = (const float*)d_in[0];
    const float* sc = (const float*)d_in[1];
    const float* di = (const float*)d_in[2];
    const float* po = (const float*)d_in[3];
    float* outp     = (float*)d_out;
    float* wbuf     = (float*)d_ws;       // 3584 floats = 14 KB

    make_weights<<<dim3(1), dim3(256), 0, stream>>>(sc, di, po, wbuf);

    dim3 grid(W / TW, H / TH, NIMG);      // 8 x 16 x 16 = 2048 blocks
    ridgelet_conv<<<grid, dim3(256), 0, stream>>>(x, wbuf, outp);
}